// Round 1
// baseline (4405.281 us; speedup 1.0000x reference)
//
#include <hip/hip_runtime.h>
#include <math.h>

// ============================================================================
// PCA + LSTM encoder/decoder on MI355X.
// Strategy: all GEMMs via mfma_f32_16x16x32_bf16 with 3-term split-bf16
// (hi/lo) operands => ~fp32 accuracy. Weights pre-transposed & gate-interleaved
// so the LSTM cell update fuses into the GEMM epilogue (1 kernel per step).
// h double-buffered across steps; c updated in place (block-owned).
// ============================================================================

typedef unsigned short US;
typedef __attribute__((ext_vector_type(8))) short bf16x8;   // 8 bf16 in 4 VGPRs
typedef __attribute__((ext_vector_type(4))) float f32x4;

__device__ __forceinline__ US f2bf(float x) {   // RNE fp32 -> bf16 bits
  unsigned int u = __float_as_uint(x);
  unsigned int r = 0x7FFFu + ((u >> 16) & 1u);
  return (US)((u + r) >> 16);
}
__device__ __forceinline__ float bf2f(US u) {
  return __uint_as_float(((unsigned int)u) << 16);
}

// ---- elementwise fp32 -> bf16 hi/lo split ----------------------------------
__global__ __launch_bounds__(256) void split_kernel(
    const float* __restrict__ in, US* __restrict__ hi, US* __restrict__ lo, int n4)
{
  int i = blockIdx.x * 256 + threadIdx.x;
  if (i >= n4) return;
  float4 v = reinterpret_cast<const float4*>(in)[i];
  US h0 = f2bf(v.x), h1 = f2bf(v.y), h2 = f2bf(v.z), h3 = f2bf(v.w);
  ushort4 hv = make_ushort4(h0, h1, h2, h3);
  ushort4 lv = make_ushort4(f2bf(v.x - bf2f(h0)), f2bf(v.y - bf2f(h1)),
                            f2bf(v.z - bf2f(h2)), f2bf(v.w - bf2f(h3)));
  reinterpret_cast<ushort4*>(hi)[i] = hv;
  reinterpret_cast<ushort4*>(lo)[i] = lv;
}

// ---- zero h[par0] and c -----------------------------------------------------
__global__ void zero_kernel(float* __restrict__ c, US* __restrict__ h0,
                            US* __restrict__ l0)
{
  int i = blockIdx.x * 256 + threadIdx.x;   // grid covers 65536 exactly
  c[i] = 0.f; h0[i] = 0; l0[i] = 0;
}

// ---- mproj[j] = sum_k mean[k] * comp[j][k] ---------------------------------
__global__ __launch_bounds__(256) void mproj_kernel(
    const float* __restrict__ mean, const float* __restrict__ comp,
    float* __restrict__ mproj)
{
  int j = blockIdx.x;
  const float* row = comp + (size_t)j * 2048;
  float s = 0.f;
  for (int k = threadIdx.x; k < 2048; k += 256) s += mean[k] * row[k];
  __shared__ float ss[4];
  #pragma unroll
  for (int o = 32; o > 0; o >>= 1) s += __shfl_down(s, o, 64);
  if ((threadIdx.x & 63) == 0) ss[threadIdx.x >> 6] = s;
  __syncthreads();
  if (threadIdx.x == 0) mproj[j] = ss[0] + ss[1] + ss[2] + ss[3];
}

// ---- build WT (gate-interleaved, transposed, split) -------------------------
// WT[j'][k], j' = 4*u + g  <->  source col g*2048+u ; k<2048 -> K, else R.
__global__ __launch_bounds__(256) void build_wt(
    const float* __restrict__ Kmat, const float* __restrict__ Rmat,
    US* __restrict__ wt_hi, US* __restrict__ wt_lo)
{
  __shared__ float tile[64][65];
  const int jblk = blockIdx.x >> 6;       // 0..127
  const int kblk = blockIdx.x & 63;       // 0..63
  const int j0 = jblk * 64;
  const int u0 = j0 >> 2;
  const int k0 = kblk * 64;
  const float* src = (k0 < 2048) ? Kmat : Rmat;
  const int ks = k0 & 2047;
  const int tid = threadIdx.x;
  const int cc = tid & 63;
  const int g = cc >> 4, uo = cc & 15;
  const int col = g * 2048 + u0 + uo;
  const int kl0 = tid >> 6;
  #pragma unroll
  for (int r = 0; r < 16; ++r) {
    int kl = r * 4 + kl0;
    tile[4 * uo + g][kl] = src[(size_t)(ks + kl) * 8192 + col];
  }
  __syncthreads();
  const int kl = tid & 63;
  const int jl0 = tid >> 6;
  #pragma unroll
  for (int r = 0; r < 16; ++r) {
    int jl = r * 4 + jl0;
    float v = tile[jl][kl];
    US hv = f2bf(v);
    size_t o = (size_t)(j0 + jl) * 4096 + (size_t)(k0 + kl);
    wt_hi[o] = hv;
    wt_lo[o] = f2bf(v - bf2f(hv));
  }
}

// ---- PCA GEMM: xs[t][b][j] = sum_k flat[m][k]*comp[j][k] - mproj[j] ---------
// m = b*64 + t.  64x64 block tile, 4 waves of 32x32, 3-term split MFMA.
__global__ __launch_bounds__(256) void pca_gemm(
    const US* __restrict__ flat_hi, const US* __restrict__ flat_lo,
    const US* __restrict__ comp_hi, const US* __restrict__ comp_lo,
    const float* __restrict__ mproj,
    US* __restrict__ xs_hi, US* __restrict__ xs_lo)
{
  const int tid = threadIdx.x;
  const int w = tid >> 6, l = tid & 63;
  const int mh = w & 1, nh = w >> 1;
  const int bm = blockIdx.x & 31, bn = blockIdx.x >> 5;
  const int l16 = l & 15, lq = l >> 4;

  const int ar0 = bm * 64 + mh * 32 + l16;
  const int br0 = bn * 64 + nh * 32 + l16;
  const US* a0h = flat_hi + (size_t)ar0 * 2048 + lq * 8;
  const US* a0l = flat_lo + (size_t)ar0 * 2048 + lq * 8;
  const US* a1h = a0h + 16 * 2048;
  const US* a1l = a0l + 16 * 2048;
  const US* b0h = comp_hi + (size_t)br0 * 2048 + lq * 8;
  const US* b0l = comp_lo + (size_t)br0 * 2048 + lq * 8;
  const US* b1h = b0h + 16 * 2048;
  const US* b1l = b0l + 16 * 2048;

  f32x4 acc00 = {0.f,0.f,0.f,0.f}, acc01 = {0.f,0.f,0.f,0.f};
  f32x4 acc10 = {0.f,0.f,0.f,0.f}, acc11 = {0.f,0.f,0.f,0.f};

  #pragma unroll 2
  for (int kk = 0; kk < 2048; kk += 32) {
    bf16x8 va0h = *reinterpret_cast<const bf16x8*>(a0h + kk);
    bf16x8 va0l = *reinterpret_cast<const bf16x8*>(a0l + kk);
    bf16x8 va1h = *reinterpret_cast<const bf16x8*>(a1h + kk);
    bf16x8 va1l = *reinterpret_cast<const bf16x8*>(a1l + kk);
    bf16x8 vb0h = *reinterpret_cast<const bf16x8*>(b0h + kk);
    bf16x8 vb0l = *reinterpret_cast<const bf16x8*>(b0l + kk);
    bf16x8 vb1h = *reinterpret_cast<const bf16x8*>(b1h + kk);
    bf16x8 vb1l = *reinterpret_cast<const bf16x8*>(b1l + kk);
    acc00 = __builtin_amdgcn_mfma_f32_16x16x32_bf16(va0h, vb0h, acc00, 0,0,0);
    acc01 = __builtin_amdgcn_mfma_f32_16x16x32_bf16(va0h, vb1h, acc01, 0,0,0);
    acc10 = __builtin_amdgcn_mfma_f32_16x16x32_bf16(va1h, vb0h, acc10, 0,0,0);
    acc11 = __builtin_amdgcn_mfma_f32_16x16x32_bf16(va1h, vb1h, acc11, 0,0,0);
    acc00 = __builtin_amdgcn_mfma_f32_16x16x32_bf16(va0l, vb0h, acc00, 0,0,0);
    acc01 = __builtin_amdgcn_mfma_f32_16x16x32_bf16(va0l, vb1h, acc01, 0,0,0);
    acc10 = __builtin_amdgcn_mfma_f32_16x16x32_bf16(va1l, vb0h, acc10, 0,0,0);
    acc11 = __builtin_amdgcn_mfma_f32_16x16x32_bf16(va1l, vb1h, acc11, 0,0,0);
    acc00 = __builtin_amdgcn_mfma_f32_16x16x32_bf16(va0h, vb0l, acc00, 0,0,0);
    acc01 = __builtin_amdgcn_mfma_f32_16x16x32_bf16(va0h, vb1l, acc01, 0,0,0);
    acc10 = __builtin_amdgcn_mfma_f32_16x16x32_bf16(va1h, vb0l, acc10, 0,0,0);
    acc11 = __builtin_amdgcn_mfma_f32_16x16x32_bf16(va1h, vb1l, acc11, 0,0,0);
  }

  #pragma unroll
  for (int mt = 0; mt < 2; ++mt) {
    #pragma unroll
    for (int nt = 0; nt < 2; ++nt) {
      f32x4 acc = (mt == 0) ? (nt == 0 ? acc00 : acc01)
                            : (nt == 0 ? acc10 : acc11);
      int j = bn * 64 + nh * 32 + nt * 16 + l16;
      float mp = mproj[j];
      #pragma unroll
      for (int r = 0; r < 4; ++r) {
        int m = bm * 64 + mh * 32 + mt * 16 + lq * 4 + r;
        float v = acc[r] - mp;
        int t = m & 63, b = m >> 6;
        size_t o = ((size_t)(t * 32 + b)) * 2048 + j;
        US hv = f2bf(v);
        xs_hi[o] = hv;
        xs_lo[o] = f2bf(v - bf2f(hv));
      }
    }
  }
}

// ---- one LSTM step: z = [x;h] @ WT^T + bias ; fused cell update -------------
// grid 256 blocks (32 cols j' each = 8 units), 512 thr = 8 waves:
// wave w: nh = w&1 (16-col group), kq = w>>1 (K quarter of 4096).
__global__ __launch_bounds__(512) void lstm_step(
    const US* __restrict__ xa_hi, const US* __restrict__ xa_lo,   // x part (32x2048)
    const US* __restrict__ hr_hi, const US* __restrict__ hr_lo,   // h part (32x2048)
    const US* __restrict__ wt_hi, const US* __restrict__ wt_lo,   // 8192x4096
    const float* __restrict__ bias, float* __restrict__ cst,
    US* __restrict__ ho_hi, US* __restrict__ ho_lo,
    float* __restrict__ pred, int p)
{
  __shared__ float red[6][64][9];   // cross-wave K reduction (padded)
  __shared__ float zbuf[32][33];    // z tile [m][j'_local]
  const int tid = threadIdx.x;
  const int w = tid >> 6, l = tid & 63;
  const int nh = w & 1, kq = w >> 1;
  const int l16 = l & 15, lq = l >> 4;

  const US* ah_src = (kq < 2) ? xa_hi : hr_hi;
  const US* al_src = (kq < 2) ? xa_lo : hr_lo;
  const int akoff = (kq & 1) * 1024 + lq * 8;
  const US* a0h = ah_src + l16 * 2048 + akoff;
  const US* a0l = al_src + l16 * 2048 + akoff;
  const US* a1h = a0h + 16 * 2048;
  const US* a1l = a0l + 16 * 2048;

  const int jb = blockIdx.x * 32 + nh * 16 + l16;
  const US* bh_ptr = wt_hi + (size_t)jb * 4096 + kq * 1024 + lq * 8;
  const US* bl_ptr = wt_lo + (size_t)jb * 4096 + kq * 1024 + lq * 8;

  f32x4 acc0 = {0.f,0.f,0.f,0.f}, acc1 = {0.f,0.f,0.f,0.f};

  #pragma unroll 4
  for (int kk = 0; kk < 1024; kk += 32) {
    bf16x8 va0h = *reinterpret_cast<const bf16x8*>(a0h + kk);
    bf16x8 va0l = *reinterpret_cast<const bf16x8*>(a0l + kk);
    bf16x8 va1h = *reinterpret_cast<const bf16x8*>(a1h + kk);
    bf16x8 va1l = *reinterpret_cast<const bf16x8*>(a1l + kk);
    bf16x8 vbh  = *reinterpret_cast<const bf16x8*>(bh_ptr + kk);
    bf16x8 vbl  = *reinterpret_cast<const bf16x8*>(bl_ptr + kk);
    acc0 = __builtin_amdgcn_mfma_f32_16x16x32_bf16(va0h, vbh, acc0, 0,0,0);
    acc1 = __builtin_amdgcn_mfma_f32_16x16x32_bf16(va1h, vbh, acc1, 0,0,0);
    acc0 = __builtin_amdgcn_mfma_f32_16x16x32_bf16(va0l, vbh, acc0, 0,0,0);
    acc1 = __builtin_amdgcn_mfma_f32_16x16x32_bf16(va1l, vbh, acc1, 0,0,0);
    acc0 = __builtin_amdgcn_mfma_f32_16x16x32_bf16(va0h, vbl, acc0, 0,0,0);
    acc1 = __builtin_amdgcn_mfma_f32_16x16x32_bf16(va1h, vbl, acc1, 0,0,0);
  }

  if (kq > 0) {
    int slot = (kq - 1) * 2 + nh;
    #pragma unroll
    for (int r = 0; r < 4; ++r) {
      red[slot][l][r]     = acc0[r];
      red[slot][l][r + 4] = acc1[r];
    }
  }
  __syncthreads();
  if (kq == 0) {
    #pragma unroll
    for (int q = 0; q < 3; ++q) {
      #pragma unroll
      for (int r = 0; r < 4; ++r) {
        acc0[r] += red[q * 2 + nh][l][r];
        acc1[r] += red[q * 2 + nh][l][r + 4];
      }
    }
    #pragma unroll
    for (int r = 0; r < 4; ++r) {
      zbuf[lq * 4 + r][nh * 16 + l16]      = acc0[r];
      zbuf[lq * 4 + r + 16][nh * 16 + l16] = acc1[r];
    }
  }
  __syncthreads();

  if (tid < 256) {
    int m = tid >> 3, ul = tid & 7;
    int u = blockIdx.x * 8 + ul;
    float zi = zbuf[m][ul * 4 + 0] + bias[u];
    float zf = zbuf[m][ul * 4 + 1] + bias[u + 2048];
    float zg = zbuf[m][ul * 4 + 2] + bias[u + 4096];
    float zo = zbuf[m][ul * 4 + 3] + bias[u + 6144];
    float gi = 1.f / (1.f + expf(-zi));
    float gf = 1.f / (1.f + expf(-zf));
    float gg = tanhf(zg);
    float go = 1.f / (1.f + expf(-zo));
    float cn = gf * cst[m * 2048 + u] + gi * gg;
    float hn = go * tanhf(cn);
    cst[m * 2048 + u] = cn;
    US hh = f2bf(hn);
    ho_hi[m * 2048 + u] = hh;
    ho_lo[m * 2048 + u] = f2bf(hn - bf2f(hh));
    if (p >= 0) pred[(size_t)(m * 24 + p) * 2048 + u] = hn;
  }
}

// ============================================================================
extern "C" void kernel_launch(void* const* d_in, const int* in_sizes, int n_in,
                              void* d_out, int out_size, void* d_ws, size_t ws_size,
                              hipStream_t stream)
{
  const float* inputs = (const float*)d_in[0];   // (32,64,2048,1)
  const float* comp   = (const float*)d_in[1];   // (2048,2048)
  const float* mean   = (const float*)d_in[2];   // (2048,)
  const float* Kmat   = (const float*)d_in[3];   // (2048,8192)
  const float* Rmat   = (const float*)d_in[4];   // (2048,8192)
  const float* bias   = (const float*)d_in[5];   // (8192,)
  float* out = (float*)d_out;                    // (32,24,2048)

  // workspace carve-up (~177 MB)
  char* pws = (char*)d_ws;
  auto alloc = [&](size_t bytes) {
    char* r = pws; pws += (bytes + 255) & ~(size_t)255; return r;
  };
  US* WT_hi   = (US*)alloc((size_t)8192 * 4096 * 2);
  US* WT_lo   = (US*)alloc((size_t)8192 * 4096 * 2);
  US* comp_hi = (US*)alloc((size_t)2048 * 2048 * 2);
  US* comp_lo = (US*)alloc((size_t)2048 * 2048 * 2);
  US* flat_hi = (US*)alloc((size_t)2048 * 2048 * 2);
  US* flat_lo = (US*)alloc((size_t)2048 * 2048 * 2);
  US* xs_hi   = (US*)alloc((size_t)64 * 32 * 2048 * 2);
  US* xs_lo   = (US*)alloc((size_t)64 * 32 * 2048 * 2);
  float* mproj = (float*)alloc(2048 * 4);
  float* cbuf  = (float*)alloc((size_t)32 * 2048 * 4);
  US* hh[2], *hl[2];
  hh[0] = (US*)alloc((size_t)32 * 2048 * 2);
  hl[0] = (US*)alloc((size_t)32 * 2048 * 2);
  hh[1] = (US*)alloc((size_t)32 * 2048 * 2);
  hl[1] = (US*)alloc((size_t)32 * 2048 * 2);

  // prep
  split_kernel<<<4096, 256, 0, stream>>>(inputs, flat_hi, flat_lo, 1048576);
  split_kernel<<<4096, 256, 0, stream>>>(comp,   comp_hi, comp_lo, 1048576);
  mproj_kernel<<<2048, 256, 0, stream>>>(mean, comp, mproj);
  build_wt<<<8192, 256, 0, stream>>>(Kmat, Rmat, WT_hi, WT_lo);
  zero_kernel<<<256, 256, 0, stream>>>(cbuf, hh[0], hl[0]);
  pca_gemm<<<1024, 256, 0, stream>>>(flat_hi, flat_lo, comp_hi, comp_lo,
                                     mproj, xs_hi, xs_lo);

  // 64 encoder + 24 decoder steps (decoder feeds x = h)
  for (int s = 0; s < 88; ++s) {
    int par = s & 1;
    const US* xaH; const US* xaL;
    if (s < 64) {
      xaH = xs_hi + (size_t)s * 32 * 2048;
      xaL = xs_lo + (size_t)s * 32 * 2048;
    } else {
      xaH = hh[par];
      xaL = hl[par];
    }
    lstm_step<<<256, 512, 0, stream>>>(xaH, xaL, hh[par], hl[par],
                                       WT_hi, WT_lo, bias, cbuf,
                                       hh[1 - par], hl[1 - par],
                                       out, s - 64);
  }
}

// Round 2
// 2583.880 us; speedup vs baseline: 1.7049x; 1.7049x over previous
//
#include <hip/hip_runtime.h>
#include <math.h>

// ============================================================================
// PCA + LSTM encoder/decoder on MI355X.
//  - All GEMMs: mfma_f32_16x16x32_bf16, 3-term split-bf16 (hi/lo) ~ fp32 acc.
//  - Encoder x@K precomputed for all 64 steps in ONE GEMM (zx).
//  - Decoder x == h  =>  z = h @ (K+R): one summed matrix (Wsum).
//  - Per-step kernel reads only ONE 64 MiB weight matrix; cell update fused.
//  - 128-tile GEMM with global_load_lds(16B) staging + XOR-swizzled LDS.
// ============================================================================

typedef unsigned short US;
typedef __attribute__((ext_vector_type(8))) short bf16x8;
typedef __attribute__((ext_vector_type(4))) float f32x4;

typedef __attribute__((address_space(3))) unsigned int as3_uint;
typedef __attribute__((address_space(1))) unsigned int as1_uint;

#define MFMA(a, b, c) __builtin_amdgcn_mfma_f32_16x16x32_bf16(a, b, c, 0, 0, 0)

__device__ __forceinline__ US f2bf(float x) {   // RNE fp32 -> bf16 bits
  unsigned int u = __float_as_uint(x);
  unsigned int r = 0x7FFFu + ((u >> 16) & 1u);
  return (US)((u + r) >> 16);
}
__device__ __forceinline__ float bf2f(US u) {
  return __uint_as_float(((unsigned int)u) << 16);
}

__device__ __forceinline__ void gl_lds16(const US* g, US* l) {
  __builtin_amdgcn_global_load_lds((const as1_uint*)g, (as3_uint*)l, 16, 0, 0);
}

// ---- elementwise fp32 -> bf16 hi/lo split ----------------------------------
__global__ __launch_bounds__(256) void split_kernel(
    const float* __restrict__ in, US* __restrict__ hi, US* __restrict__ lo, int n4)
{
  int i = blockIdx.x * 256 + threadIdx.x;
  if (i >= n4) return;
  float4 v = reinterpret_cast<const float4*>(in)[i];
  US h0 = f2bf(v.x), h1 = f2bf(v.y), h2 = f2bf(v.z), h3 = f2bf(v.w);
  ushort4 hv = make_ushort4(h0, h1, h2, h3);
  ushort4 lv = make_ushort4(f2bf(v.x - bf2f(h0)), f2bf(v.y - bf2f(h1)),
                            f2bf(v.z - bf2f(h2)), f2bf(v.w - bf2f(h3)));
  reinterpret_cast<ushort4*>(hi)[i] = hv;
  reinterpret_cast<ushort4*>(lo)[i] = lv;
}

// ---- zero h[par0] and c -----------------------------------------------------
__global__ void zero_kernel(float* __restrict__ c, US* __restrict__ h0,
                            US* __restrict__ l0)
{
  int i = blockIdx.x * 256 + threadIdx.x;   // grid covers 65536 exactly
  c[i] = 0.f; h0[i] = 0; l0[i] = 0;
}

// ---- mproj[j] = sum_k mean[k] * comp[j][k] ---------------------------------
__global__ __launch_bounds__(256) void mproj_kernel(
    const float* __restrict__ mean, const float* __restrict__ comp,
    float* __restrict__ mproj)
{
  int j = blockIdx.x;
  const float* row = comp + (size_t)j * 2048;
  float s = 0.f;
  for (int k = threadIdx.x; k < 2048; k += 256) s += mean[k] * row[k];
  __shared__ float ss[4];
  #pragma unroll
  for (int o = 32; o > 0; o >>= 1) s += __shfl_down(s, o, 64);
  if ((threadIdx.x & 63) == 0) ss[threadIdx.x >> 6] = s;
  __syncthreads();
  if (threadIdx.x == 0) mproj[j] = ss[0] + ss[1] + ss[2] + ss[3];
}

// ---- build T[j'][k] gate-interleaved transpose, k-extent 2048, split -------
// j' = 4*u + g  <->  source col g*2048+u.  SUM: srcA + srcB.
template<bool SUM>
__global__ __launch_bounds__(256) void build_t(
    const float* __restrict__ srcA, const float* __restrict__ srcB,
    US* __restrict__ t_hi, US* __restrict__ t_lo)
{
  __shared__ float tile[64][65];
  const int jblk = blockIdx.x >> 5;       // 0..127
  const int kblk = blockIdx.x & 31;       // 0..31
  const int j0 = jblk * 64;
  const int u0 = j0 >> 2;
  const int k0 = kblk * 64;
  const int tid = threadIdx.x;
  const int cc = tid & 63;
  const int g = cc >> 4, uo = cc & 15;
  const int col = g * 2048 + u0 + uo;
  const int kl0 = tid >> 6;
  #pragma unroll
  for (int r = 0; r < 16; ++r) {
    int kl = r * 4 + kl0;
    float v = srcA[(size_t)(k0 + kl) * 8192 + col];
    if (SUM) v += srcB[(size_t)(k0 + kl) * 8192 + col];
    tile[4 * uo + g][kl] = v;
  }
  __syncthreads();
  const int kl = tid & 63;
  const int jl0 = tid >> 6;
  #pragma unroll
  for (int r = 0; r < 16; ++r) {
    int jl = r * 4 + jl0;
    float v = tile[jl][kl];
    US hv = f2bf(v);
    size_t o = (size_t)(j0 + jl) * 2048 + (size_t)(k0 + kl);
    t_hi[o] = hv;
    t_lo[o] = f2bf(v - bf2f(hv));
  }
}

// ---- 128-row tiled GEMM, LDS-staged via global_load_lds, XOR swizzle -------
// C[m][n] = sum_k A[m][k]*B[n][k], K = 2048, 3-term split.
// NT: n-tiles per wave (2 -> BN=64, 4 -> BN=128). 256 thr = 4 waves (2m x 2n).
// EPI 0: pca (subtract mproj, remap rows b*64+t -> t*32+b, split-store)
// EPI 1: plain fp32 store.
template<int NT, int EPI>
__global__ __launch_bounds__(256, 2) void gemm128(
    const US* __restrict__ Ah, const US* __restrict__ Al,
    const US* __restrict__ Bh, const US* __restrict__ Bl,
    const float* __restrict__ mproj,
    US* __restrict__ out0, US* __restrict__ out1,
    int MB, int ldo)
{
  constexpr int BN = NT * 32;
  __shared__ US sAh[128 * 64], sAl[128 * 64];
  __shared__ US sBh[BN * 64],  sBl[BN * 64];
  const int tid = threadIdx.x;
  const int w = tid >> 6, l = tid & 63;
  const int l16 = l & 15, lq = l >> 4;
  const int bm = blockIdx.x % MB, bn = blockIdx.x / MB;
  const int wm = w & 1, wn = w >> 1;
  const int AR0 = bm * 128, BR0 = bn * BN;

  f32x4 acc[4][NT];
  #pragma unroll
  for (int i = 0; i < 4; ++i)
    #pragma unroll
    for (int j = 0; j < NT; ++j) acc[i][j] = {0.f, 0.f, 0.f, 0.f};

  for (int k0 = 0; k0 < 2048; k0 += 64) {
    // stage 4 tensors: chunk c -> lds 16B slot c; global k-chunk = (c&7)^(row&7)
    {
      #pragma unroll
      for (int i = 0; i < 4; ++i) {          // A tiles: 128 rows
        int c = (w * 4 + i) * 64 + l;
        int row = c >> 3, kc = c & 7;
        size_t go = (size_t)(AR0 + row) * 2048 + (k0 + ((kc ^ (row & 7)) << 3));
        gl_lds16(Ah + go, sAh + (w * 4 + i) * 512);
        gl_lds16(Al + go, sAl + (w * 4 + i) * 512);
      }
      constexpr int IPW = BN >> 5;           // B tiles: BN rows
      #pragma unroll
      for (int i = 0; i < IPW; ++i) {
        int c = (w * IPW + i) * 64 + l;
        int row = c >> 3, kc = c & 7;
        size_t go = (size_t)(BR0 + row) * 2048 + (k0 + ((kc ^ (row & 7)) << 3));
        gl_lds16(Bh + go, sBh + (w * IPW + i) * 512);
        gl_lds16(Bl + go, sBl + (w * IPW + i) * 512);
      }
    }
    __syncthreads();   // drains vmcnt(0) before barrier
    #pragma unroll
    for (int ks = 0; ks < 2; ++ks) {
      const int kb = ks * 64 + lq * 16;      // byte offset in 128B row
      bf16x8 ah[4], al[4], bh[NT], bl[NT];
      #pragma unroll
      for (int mt = 0; mt < 4; ++mt) {
        int r = wm * 64 + mt * 16 + l16;
        int off = r * 64 + ((kb ^ ((r & 7) << 4)) >> 1);
        ah[mt] = *reinterpret_cast<const bf16x8*>(sAh + off);
        al[mt] = *reinterpret_cast<const bf16x8*>(sAl + off);
      }
      #pragma unroll
      for (int nt = 0; nt < NT; ++nt) {
        int r = wn * (BN / 2) + nt * 16 + l16;
        int off = r * 64 + ((kb ^ ((r & 7) << 4)) >> 1);
        bh[nt] = *reinterpret_cast<const bf16x8*>(sBh + off);
        bl[nt] = *reinterpret_cast<const bf16x8*>(sBl + off);
      }
      #pragma unroll
      for (int mt = 0; mt < 4; ++mt)
        #pragma unroll
        for (int nt = 0; nt < NT; ++nt) {
          acc[mt][nt] = MFMA(ah[mt], bh[nt], acc[mt][nt]);
          acc[mt][nt] = MFMA(al[mt], bh[nt], acc[mt][nt]);
          acc[mt][nt] = MFMA(ah[mt], bl[nt], acc[mt][nt]);
        }
    }
    __syncthreads();   // all reads done before next stage overwrites
  }

  #pragma unroll
  for (int mt = 0; mt < 4; ++mt)
    #pragma unroll
    for (int nt = 0; nt < NT; ++nt) {
      int j = BR0 + wn * (BN / 2) + nt * 16 + l16;
      float mp = (EPI == 0) ? mproj[j] : 0.f;
      #pragma unroll
      for (int r = 0; r < 4; ++r) {
        int m = AR0 + wm * 64 + mt * 16 + lq * 4 + r;
        float v = acc[mt][nt][r] - mp;
        if constexpr (EPI == 0) {
          int t = m & 63, b = m >> 6;
          size_t o = (size_t)(t * 32 + b) * ldo + j;
          US hv = f2bf(v);
          out0[o] = hv;
          out1[o] = f2bf(v - bf2f(hv));
        } else {
          ((float*)out0)[(size_t)m * ldo + j] = v;
        }
      }
    }
}

// ---- one LSTM step: z = zx + h @ W^T + bias ; fused cell update ------------
// grid 512 blocks (16 j' = 4 units each), 512 thr = 8 waves, wave = K/8 slice.
__global__ __launch_bounds__(512, 4) void lstm_step(
    const US* __restrict__ h_hi, const US* __restrict__ h_lo,   // (32,2048)
    const US* __restrict__ w_hi, const US* __restrict__ w_lo,   // (8192,2048)
    const float* __restrict__ zx,                               // (32,8192) or null
    const float* __restrict__ bias, float* __restrict__ cst,
    US* __restrict__ ho_hi, US* __restrict__ ho_lo,
    float* __restrict__ pred, int p)
{
  __shared__ float red[7][64][9];
  __shared__ float zbuf[32][17];
  const int tid = threadIdx.x;
  const int kq = tid >> 6, l = tid & 63;
  const int l16 = l & 15, lq = l >> 4;

  const US* a0h = h_hi + l16 * 2048 + kq * 256 + lq * 8;
  const US* a0l = h_lo + l16 * 2048 + kq * 256 + lq * 8;
  const US* a1h = a0h + 16 * 2048;
  const US* a1l = a0l + 16 * 2048;
  const int jb = blockIdx.x * 16 + l16;
  const US* bhp = w_hi + (size_t)jb * 2048 + kq * 256 + lq * 8;
  const US* blp = w_lo + (size_t)jb * 2048 + kq * 256 + lq * 8;

  f32x4 acc0 = {0.f,0.f,0.f,0.f}, acc1 = {0.f,0.f,0.f,0.f};
  #pragma unroll
  for (int kk = 0; kk < 256; kk += 32) {
    bf16x8 va0h = *reinterpret_cast<const bf16x8*>(a0h + kk);
    bf16x8 va0l = *reinterpret_cast<const bf16x8*>(a0l + kk);
    bf16x8 va1h = *reinterpret_cast<const bf16x8*>(a1h + kk);
    bf16x8 va1l = *reinterpret_cast<const bf16x8*>(a1l + kk);
    bf16x8 vbh  = *reinterpret_cast<const bf16x8*>(bhp + kk);
    bf16x8 vbl  = *reinterpret_cast<const bf16x8*>(blp + kk);
    acc0 = MFMA(va0h, vbh, acc0);
    acc1 = MFMA(va1h, vbh, acc1);
    acc0 = MFMA(va0l, vbh, acc0);
    acc1 = MFMA(va1l, vbh, acc1);
    acc0 = MFMA(va0h, vbl, acc0);
    acc1 = MFMA(va1h, vbl, acc1);
  }

  if (kq > 0) {
    #pragma unroll
    for (int r = 0; r < 4; ++r) {
      red[kq - 1][l][r]     = acc0[r];
      red[kq - 1][l][r + 4] = acc1[r];
    }
  }
  __syncthreads();
  if (kq == 0) {
    #pragma unroll
    for (int q = 0; q < 7; ++q)
      #pragma unroll
      for (int r = 0; r < 4; ++r) {
        acc0[r] += red[q][l][r];
        acc1[r] += red[q][l][r + 4];
      }
    #pragma unroll
    for (int r = 0; r < 4; ++r) {
      zbuf[lq * 4 + r][l16]      = acc0[r];
      zbuf[lq * 4 + r + 16][l16] = acc1[r];
    }
  }
  __syncthreads();

  if (tid < 128) {
    int m = tid >> 2, ul = tid & 3;
    int u = blockIdx.x * 4 + ul;
    float zi = zbuf[m][ul * 4 + 0] + bias[u];
    float zf = zbuf[m][ul * 4 + 1] + bias[u + 2048];
    float zg = zbuf[m][ul * 4 + 2] + bias[u + 4096];
    float zo = zbuf[m][ul * 4 + 3] + bias[u + 6144];
    if (zx) {
      const float* zr = zx + (size_t)m * 8192 + (size_t)u * 4;
      zi += zr[0]; zf += zr[1]; zg += zr[2]; zo += zr[3];
    }
    float gi = 1.f / (1.f + expf(-zi));
    float gf = 1.f / (1.f + expf(-zf));
    float gg = tanhf(zg);
    float go = 1.f / (1.f + expf(-zo));
    float cn = gf * cst[m * 2048 + u] + gi * gg;
    float hn = go * tanhf(cn);
    cst[m * 2048 + u] = cn;
    US hh = f2bf(hn);
    ho_hi[m * 2048 + u] = hh;
    ho_lo[m * 2048 + u] = f2bf(hn - bf2f(hh));
    if (p >= 0) pred[(size_t)(m * 24 + p) * 2048 + u] = hn;
  }
}

// ============================================================================
extern "C" void kernel_launch(void* const* d_in, const int* in_sizes, int n_in,
                              void* d_out, int out_size, void* d_ws, size_t ws_size,
                              hipStream_t stream)
{
  const float* inputs = (const float*)d_in[0];   // (32,64,2048,1)
  const float* comp   = (const float*)d_in[1];   // (2048,2048)
  const float* mean   = (const float*)d_in[2];   // (2048,)
  const float* Kmat   = (const float*)d_in[3];   // (2048,8192)
  const float* Rmat   = (const float*)d_in[4];   // (2048,8192)
  const float* bias   = (const float*)d_in[5];   // (8192,)
  float* out = (float*)d_out;                    // (32,24,2048)

  // ---- workspace layout (~177 MiB, time-multiplexed) ----
  const size_t MiB = 1024 * 1024;
  char* base = (char*)d_ws;
  US*    KT_hi  = (US*)(base);                 // later: RT_hi
  US*    KT_lo  = (US*)(base + 32 * MiB);      // later: RT_lo
  float* zx     = (float*)(base + 64 * MiB);   // 64 MiB; later: WST
  US*    WST_hi = (US*)(base + 64 * MiB);
  US*    WST_lo = (US*)(base + 96 * MiB);
  US*    RT_hi  = KT_hi;
  US*    RT_lo  = KT_lo;
  char*  C = base + 128 * MiB;
  US* comp_hi = (US*)(C);
  US* comp_lo = (US*)(C + 8 * MiB);
  US* flat_hi = (US*)(C + 16 * MiB);
  US* flat_lo = (US*)(C + 24 * MiB);
  US* xs_hi   = (US*)(C + 32 * MiB);
  US* xs_lo   = (US*)(C + 40 * MiB);
  char* Mz = base + 176 * MiB;
  float* mproj = (float*)(Mz);
  float* cbuf  = (float*)(Mz + 64 * 1024);
  US* hh[2]; US* hl[2];
  hh[0] = (US*)(Mz + 384 * 1024);
  hl[0] = (US*)(Mz + 512 * 1024);
  hh[1] = (US*)(Mz + 640 * 1024);
  hl[1] = (US*)(Mz + 768 * 1024);

  // ---- prep ----
  split_kernel<<<4096, 256, 0, stream>>>(inputs, flat_hi, flat_lo, 1048576);
  split_kernel<<<4096, 256, 0, stream>>>(comp,   comp_hi, comp_lo, 1048576);
  mproj_kernel<<<2048, 256, 0, stream>>>(mean, comp, mproj);
  build_t<false><<<4096, 256, 0, stream>>>(Kmat, nullptr, KT_hi, KT_lo);
  zero_kernel<<<256, 256, 0, stream>>>(cbuf, hh[0], hl[0]);

  // xs = (flat - mean) @ comp^T   (2048 x 2048)
  gemm128<2, 0><<<512, 256, 0, stream>>>(flat_hi, flat_lo, comp_hi, comp_lo,
                                         mproj, xs_hi, xs_lo, 16, 2048);
  // zx = xs @ K  (2048 x 8192, gate-interleaved cols)
  gemm128<4, 1><<<1024, 256, 0, stream>>>(xs_hi, xs_lo, KT_hi, KT_lo,
                                          nullptr, (US*)zx, nullptr, 16, 8192);
  // RT over the (now dead) KT region
  build_t<false><<<4096, 256, 0, stream>>>(Rmat, nullptr, RT_hi, RT_lo);

  // ---- 64 encoder steps: z = zx[s] + h @ R^T ----
  for (int s = 0; s < 64; ++s) {
    int par = s & 1;
    lstm_step<<<512, 512, 0, stream>>>(hh[par], hl[par], RT_hi, RT_lo,
                                       zx + (size_t)s * 32 * 8192,
                                       bias, cbuf, hh[1 - par], hl[1 - par],
                                       out, -1);
  }
  // WST = (K + R)^T over the (now dead) zx region
  build_t<true><<<4096, 256, 0, stream>>>(Kmat, Rmat, WST_hi, WST_lo);
  // ---- 24 decoder steps: z = h @ (K+R)^T ----
  for (int s = 64; s < 88; ++s) {
    int par = s & 1;
    lstm_step<<<512, 512, 0, stream>>>(hh[par], hl[par], WST_hi, WST_lo,
                                       nullptr,
                                       bias, cbuf, hh[1 - par], hl[1 - par],
                                       out, s - 64);
  }
}

// Round 3
// 1722.320 us; speedup vs baseline: 2.5578x; 1.5002x over previous
//
#include <hip/hip_runtime.h>
#include <math.h>

// ============================================================================
// PCA + LSTM encoder/decoder on MI355X.
//  - GEMMs: mfma_f32_16x16x32_bf16, 3-term split-bf16 (hi/lo) ~ fp32 accuracy.
//  - Encoder x@K precomputed for all 64 steps in ONE GEMM (zx).
//  - Decoder x == h  =>  z = h @ (K+R).
//  - lstm_step: weights stored FRAGMENT-LINEAR (lane-major) so every weight
//    load is a fully-coalesced 1KB wave load direct to VGPRs. No LDS staging.
//  - gemm128: LDS-staged via global_load_lds + XCD-aware block swizzle.
// ============================================================================

typedef unsigned short US;
typedef __attribute__((ext_vector_type(8))) short bf16x8;
typedef __attribute__((ext_vector_type(4))) float f32x4;

typedef __attribute__((address_space(3))) unsigned int as3_uint;
typedef __attribute__((address_space(1))) unsigned int as1_uint;

#define MFMA(a, b, c) __builtin_amdgcn_mfma_f32_16x16x32_bf16(a, b, c, 0, 0, 0)

__device__ __forceinline__ US f2bf(float x) {   // RNE fp32 -> bf16 bits
  unsigned int u = __float_as_uint(x);
  unsigned int r = 0x7FFFu + ((u >> 16) & 1u);
  return (US)((u + r) >> 16);
}
__device__ __forceinline__ float bf2f(US u) {
  return __uint_as_float(((unsigned int)u) << 16);
}

__device__ __forceinline__ void gl_lds16(const US* g, US* l) {
  __builtin_amdgcn_global_load_lds((const as1_uint*)g, (as3_uint*)l, 16, 0, 0);
}

// ---- elementwise fp32 -> bf16 hi/lo split ----------------------------------
__global__ __launch_bounds__(256) void split_kernel(
    const float* __restrict__ in, US* __restrict__ hi, US* __restrict__ lo, int n4)
{
  int i = blockIdx.x * 256 + threadIdx.x;
  if (i >= n4) return;
  float4 v = reinterpret_cast<const float4*>(in)[i];
  US h0 = f2bf(v.x), h1 = f2bf(v.y), h2 = f2bf(v.z), h3 = f2bf(v.w);
  ushort4 hv = make_ushort4(h0, h1, h2, h3);
  ushort4 lv = make_ushort4(f2bf(v.x - bf2f(h0)), f2bf(v.y - bf2f(h1)),
                            f2bf(v.z - bf2f(h2)), f2bf(v.w - bf2f(h3)));
  reinterpret_cast<ushort4*>(hi)[i] = hv;
  reinterpret_cast<ushort4*>(lo)[i] = lv;
}

// ---- zero c and h-frag buffers ---------------------------------------------
__global__ void zero_kernel(float* __restrict__ c, US* __restrict__ h0,
                            US* __restrict__ l0)
{
  int i = blockIdx.x * 256 + threadIdx.x;   // grid covers 65536 exactly
  c[i] = 0.f; h0[i] = 0; l0[i] = 0;
}

// ---- mproj[j] = sum_k mean[k] * comp[j][k] ---------------------------------
__global__ __launch_bounds__(256) void mproj_kernel(
    const float* __restrict__ mean, const float* __restrict__ comp,
    float* __restrict__ mproj)
{
  int j = blockIdx.x;
  const float* row = comp + (size_t)j * 2048;
  float s = 0.f;
  for (int k = threadIdx.x; k < 2048; k += 256) s += mean[k] * row[k];
  __shared__ float ss[4];
  #pragma unroll
  for (int o = 32; o > 0; o >>= 1) s += __shfl_down(s, o, 64);
  if ((threadIdx.x & 63) == 0) ss[threadIdx.x >> 6] = s;
  __syncthreads();
  if (threadIdx.x == 0) mproj[j] = ss[0] + ss[1] + ss[2] + ss[3];
}

// ---- build KT[j'][k] row-major gate-interleaved transpose (for zx GEMM) ----
// j' = 4*u + g  <->  source col g*2048+u.
__global__ __launch_bounds__(256) void build_kt(
    const float* __restrict__ src, US* __restrict__ t_hi, US* __restrict__ t_lo)
{
  __shared__ float tile[64][65];
  const int jblk = blockIdx.x >> 5;       // 0..127
  const int kblk = blockIdx.x & 31;       // 0..31
  const int j0 = jblk * 64;
  const int u0 = j0 >> 2;
  const int k0 = kblk * 64;
  const int tid = threadIdx.x;
  const int cc = tid & 63;
  const int g = cc >> 4, uo = cc & 15;
  const int col = g * 2048 + u0 + uo;
  const int kl0 = tid >> 6;
  #pragma unroll
  for (int r = 0; r < 16; ++r) {
    int kl = r * 4 + kl0;
    tile[4 * uo + g][kl] = src[(size_t)(k0 + kl) * 8192 + col];
  }
  __syncthreads();
  const int kl = tid & 63;
  const int jl0 = tid >> 6;
  #pragma unroll
  for (int r = 0; r < 16; ++r) {
    int jl = r * 4 + jl0;
    float v = tile[jl][kl];
    US hv = f2bf(v);
    size_t o = (size_t)(j0 + jl) * 2048 + (size_t)(k0 + kl);
    t_hi[o] = hv;
    t_lo[o] = f2bf(v - bf2f(hv));
  }
}

// ---- build fragment-linear split weights W'[j'][k] -------------------------
// frag addr: jg=j'>>4; kc=k>>5; l=((k>>3)&3)*16+(j'&15); e=k&7;
//            lin = ((jg*64+kc)*64+l)*8+e.
// SUM: srcA + srcB (for K+R).  Block: 16 units x 64 k.
template<bool SUM>
__global__ __launch_bounds__(256) void build_wfrag(
    const float* __restrict__ srcA, const float* __restrict__ srcB,
    US* __restrict__ t_hi, US* __restrict__ t_lo)
{
  __shared__ float tile[64][68];          // [j'local][k_local]
  const int ub = blockIdx.x >> 5;         // 0..127 (16 units each)
  const int kb = blockIdx.x & 31;         // 0..31  (64 k each)
  const int u0 = ub * 16, k0 = kb * 64;
  const int jg0 = ub * 4, kc0 = kb * 2;
  const int tid = threadIdx.x;

  const int g = tid >> 6, r2 = (tid >> 2) & 15, c4 = tid & 3;
  #pragma unroll
  for (int rr = 0; rr < 4; ++rr) {
    int row = rr * 16 + r2;
    size_t off = (size_t)(k0 + row) * 8192 + g * 2048 + u0 + c4 * 4;
    float4 v = *reinterpret_cast<const float4*>(srcA + off);
    if (SUM) {
      float4 w = *reinterpret_cast<const float4*>(srcB + off);
      v.x += w.x; v.y += w.y; v.z += w.z; v.w += w.w;
    }
    tile[4 * (c4 * 4 + 0) + g][row] = v.x;
    tile[4 * (c4 * 4 + 1) + g][row] = v.y;
    tile[4 * (c4 * 4 + 2) + g][row] = v.z;
    tile[4 * (c4 * 4 + 3) + g][row] = v.w;
  }
  __syncthreads();

  #pragma unroll
  for (int it = 0; it < 2; ++it) {
    int idx = it * 256 + tid;
    int l = idx & 63, kcl = (idx >> 6) & 1, jgl = idx >> 7;
    int jloc = jgl * 16 + (l & 15);
    int kl = kcl * 32 + (l >> 4) * 8;
    float4 v0 = *reinterpret_cast<const float4*>(&tile[jloc][kl]);
    float4 v1 = *reinterpret_cast<const float4*>(&tile[jloc][kl + 4]);
    float f[8] = {v0.x, v0.y, v0.z, v0.w, v1.x, v1.y, v1.z, v1.w};
    unsigned int hp[4], lp[4];
    #pragma unroll
    for (int q = 0; q < 4; ++q) {
      US h0 = f2bf(f[2 * q]),     h1 = f2bf(f[2 * q + 1]);
      US s0 = f2bf(f[2 * q] - bf2f(h0));
      US s1 = f2bf(f[2 * q + 1] - bf2f(h1));
      hp[q] = (unsigned int)h0 | ((unsigned int)h1 << 16);
      lp[q] = (unsigned int)s0 | ((unsigned int)s1 << 16);
    }
    size_t base = (((size_t)(jg0 + jgl) * 64 + (kc0 + kcl)) * 64 + l) * 8;
    *reinterpret_cast<uint4*>(t_hi + base) = make_uint4(hp[0], hp[1], hp[2], hp[3]);
    *reinterpret_cast<uint4*>(t_lo + base) = make_uint4(lp[0], lp[1], lp[2], lp[3]);
  }
}

// ---- 128-row tiled GEMM, LDS-staged via global_load_lds, XOR swizzle -------
// C[m][n] = sum_k A[m][k]*B[n][k], K = 2048, 3-term split. XCD block swizzle.
template<int NT, int EPI>
__global__ __launch_bounds__(256, 2) void gemm128(
    const US* __restrict__ Ah, const US* __restrict__ Al,
    const US* __restrict__ Bh, const US* __restrict__ Bl,
    const float* __restrict__ mproj,
    US* __restrict__ out0, US* __restrict__ out1,
    int MB, int ldo)
{
  constexpr int BN = NT * 32;
  __shared__ US sAh[128 * 64], sAl[128 * 64];
  __shared__ US sBh[BN * 64],  sBl[BN * 64];
  const int tid = threadIdx.x;
  const int w = tid >> 6, l = tid & 63;
  const int l16 = l & 15, lq = l >> 4;
  // XCD-aware bijective swizzle (gridDim.x % 8 == 0): XCD x gets a
  // contiguous chunk of logical block ids -> 16 consecutive share one bn.
  const int cpx = gridDim.x >> 3;
  const int swz = (blockIdx.x & 7) * cpx + (blockIdx.x >> 3);
  const int bm = swz % MB, bn = swz / MB;
  const int wm = w & 1, wn = w >> 1;
  const int AR0 = bm * 128, BR0 = bn * BN;

  f32x4 acc[4][NT];
  #pragma unroll
  for (int i = 0; i < 4; ++i)
    #pragma unroll
    for (int j = 0; j < NT; ++j) acc[i][j] = {0.f, 0.f, 0.f, 0.f};

  for (int k0 = 0; k0 < 2048; k0 += 64) {
    {
      #pragma unroll
      for (int i = 0; i < 4; ++i) {          // A tiles: 128 rows
        int c = (w * 4 + i) * 64 + l;
        int row = c >> 3, kc = c & 7;
        size_t go = (size_t)(AR0 + row) * 2048 + (k0 + ((kc ^ (row & 7)) << 3));
        gl_lds16(Ah + go, sAh + (w * 4 + i) * 512);
        gl_lds16(Al + go, sAl + (w * 4 + i) * 512);
      }
      constexpr int IPW = BN >> 5;           // B tiles: BN rows
      #pragma unroll
      for (int i = 0; i < IPW; ++i) {
        int c = (w * IPW + i) * 64 + l;
        int row = c >> 3, kc = c & 7;
        size_t go = (size_t)(BR0 + row) * 2048 + (k0 + ((kc ^ (row & 7)) << 3));
        gl_lds16(Bh + go, sBh + (w * IPW + i) * 512);
        gl_lds16(Bl + go, sBl + (w * IPW + i) * 512);
      }
    }
    __syncthreads();
    #pragma unroll
    for (int ks = 0; ks < 2; ++ks) {
      const int kb = ks * 64 + lq * 16;
      bf16x8 ah[4], al[4], bh[NT], bl[NT];
      #pragma unroll
      for (int mt = 0; mt < 4; ++mt) {
        int r = wm * 64 + mt * 16 + l16;
        int off = r * 64 + ((kb ^ ((r & 7) << 4)) >> 1);
        ah[mt] = *reinterpret_cast<const bf16x8*>(sAh + off);
        al[mt] = *reinterpret_cast<const bf16x8*>(sAl + off);
      }
      #pragma unroll
      for (int nt = 0; nt < NT; ++nt) {
        int r = wn * (BN / 2) + nt * 16 + l16;
        int off = r * 64 + ((kb ^ ((r & 7) << 4)) >> 1);
        bh[nt] = *reinterpret_cast<const bf16x8*>(sBh + off);
        bl[nt] = *reinterpret_cast<const bf16x8*>(sBl + off);
      }
      #pragma unroll
      for (int mt = 0; mt < 4; ++mt)
        #pragma unroll
        for (int nt = 0; nt < NT; ++nt) {
          acc[mt][nt] = MFMA(ah[mt], bh[nt], acc[mt][nt]);
          acc[mt][nt] = MFMA(al[mt], bh[nt], acc[mt][nt]);
          acc[mt][nt] = MFMA(ah[mt], bl[nt], acc[mt][nt]);
        }
    }
    __syncthreads();
  }

  #pragma unroll
  for (int mt = 0; mt < 4; ++mt)
    #pragma unroll
    for (int nt = 0; nt < NT; ++nt) {
      int j = BR0 + wn * (BN / 2) + nt * 16 + l16;
      float mp = (EPI == 0) ? mproj[j] : 0.f;
      #pragma unroll
      for (int r = 0; r < 4; ++r) {
        int m = AR0 + wm * 64 + mt * 16 + lq * 4 + r;
        float v = acc[mt][nt][r] - mp;
        if constexpr (EPI == 0) {
          int t = m & 63, b = m >> 6;
          size_t o = (size_t)(t * 32 + b) * ldo + j;
          US hv = f2bf(v);
          out0[o] = hv;
          out1[o] = f2bf(v - bf2f(hv));
        } else {
          ((float*)out0)[(size_t)m * ldo + j] = v;
        }
      }
    }
}

// ---- one LSTM step: z = zx + h @ W'^T + bias ; fused cell update -----------
// Fragment-linear W and h: all loads are contiguous 1KB wave loads.
// grid 512 blocks (jg: 16 j' = 4 units), 512 thr = 8 waves = 8-way split-K.
__global__ __launch_bounds__(512, 4) void lstm_step(
    const US* __restrict__ hf_hi, const US* __restrict__ hf_lo,   // frag (32,2048)
    const US* __restrict__ wf_hi, const US* __restrict__ wf_lo,   // frag (8192,2048)
    const float* __restrict__ zx,                                 // (32,8192) or null
    const float* __restrict__ bias, float* __restrict__ cst,
    US* __restrict__ ho_hi, US* __restrict__ ho_lo,               // frag (32,2048)
    float* __restrict__ pred, int p)
{
  __shared__ float red[7][64][9];
  __shared__ float zbuf[32][17];
  const int tid = threadIdx.x;
  const int kq = tid >> 6, l = tid & 63;
  const int jg = blockIdx.x;
  const int l16 = l & 15, lq = l >> 4;

  const US* wh = wf_hi + (((size_t)jg * 64 + kq * 8) * 64 + l) * 8;
  const US* wl = wf_lo + (((size_t)jg * 64 + kq * 8) * 64 + l) * 8;
  const US* ah = hf_hi + (((size_t)kq * 16) * 64 + l) * 8;
  const US* al = hf_lo + (((size_t)kq * 16) * 64 + l) * 8;

  f32x4 acc0 = {0.f,0.f,0.f,0.f}, acc1 = {0.f,0.f,0.f,0.f};
  #pragma unroll
  for (int c = 0; c < 8; ++c) {
    bf16x8 vbh = *reinterpret_cast<const bf16x8*>(wh + c * 512);
    bf16x8 vbl = *reinterpret_cast<const bf16x8*>(wl + c * 512);
    bf16x8 a0h = *reinterpret_cast<const bf16x8*>(ah + c * 1024);
    bf16x8 a1h = *reinterpret_cast<const bf16x8*>(ah + c * 1024 + 512);
    bf16x8 a0l = *reinterpret_cast<const bf16x8*>(al + c * 1024);
    bf16x8 a1l = *reinterpret_cast<const bf16x8*>(al + c * 1024 + 512);
    acc0 = MFMA(a0h, vbh, acc0);
    acc1 = MFMA(a1h, vbh, acc1);
    acc0 = MFMA(a0l, vbh, acc0);
    acc1 = MFMA(a1l, vbh, acc1);
    acc0 = MFMA(a0h, vbl, acc0);
    acc1 = MFMA(a1h, vbl, acc1);
  }

  if (kq > 0) {
    #pragma unroll
    for (int r = 0; r < 4; ++r) {
      red[kq - 1][l][r]     = acc0[r];
      red[kq - 1][l][r + 4] = acc1[r];
    }
  }
  __syncthreads();
  if (kq == 0) {
    #pragma unroll
    for (int q = 0; q < 7; ++q)
      #pragma unroll
      for (int r = 0; r < 4; ++r) {
        acc0[r] += red[q][l][r];
        acc1[r] += red[q][l][r + 4];
      }
    #pragma unroll
    for (int r = 0; r < 4; ++r) {
      zbuf[lq * 4 + r][l16]      = acc0[r];
      zbuf[lq * 4 + r + 16][l16] = acc1[r];
    }
  }
  __syncthreads();

  if (tid < 128) {
    int m = tid >> 2, ul = tid & 3;
    int u = jg * 4 + ul;
    float zi = zbuf[m][ul * 4 + 0] + bias[u];
    float zf = zbuf[m][ul * 4 + 1] + bias[u + 2048];
    float zg = zbuf[m][ul * 4 + 2] + bias[u + 4096];
    float zo = zbuf[m][ul * 4 + 3] + bias[u + 6144];
    if (zx) {
      const float* zr = zx + (size_t)m * 8192 + (size_t)u * 4;
      zi += zr[0]; zf += zr[1]; zg += zr[2]; zo += zr[3];
    }
    float gi = 1.f / (1.f + expf(-zi));
    float gf = 1.f / (1.f + expf(-zf));
    float gg = tanhf(zg);
    float go = 1.f / (1.f + expf(-zo));
    float cn = gf * cst[m * 2048 + u] + gi * gg;
    float hn = go * tanhf(cn);
    cst[m * 2048 + u] = cn;
    // h write in fragment-linear layout for next step's A loads
    int kc = u >> 5, mh = m >> 4;
    int lw = ((u >> 3) & 3) * 16 + (m & 15);
    int e = u & 7;
    size_t hidx = (((size_t)kc * 2 + mh) * 64 + lw) * 8 + e;
    US hh = f2bf(hn);
    ho_hi[hidx] = hh;
    ho_lo[hidx] = f2bf(hn - bf2f(hh));
    if (p >= 0) pred[(size_t)(m * 24 + p) * 2048 + u] = hn;
  }
}

// ============================================================================
extern "C" void kernel_launch(void* const* d_in, const int* in_sizes, int n_in,
                              void* d_out, int out_size, void* d_ws, size_t ws_size,
                              hipStream_t stream)
{
  const float* inputs = (const float*)d_in[0];   // (32,64,2048,1)
  const float* comp   = (const float*)d_in[1];   // (2048,2048)
  const float* mean   = (const float*)d_in[2];   // (2048,)
  const float* Kmat   = (const float*)d_in[3];   // (2048,8192)
  const float* Rmat   = (const float*)d_in[4];   // (2048,8192)
  const float* bias   = (const float*)d_in[5];   // (8192,)
  float* out = (float*)d_out;                    // (32,24,2048)

  // ---- workspace layout (177 MiB, time-multiplexed) ----
  const size_t MiB = 1024 * 1024;
  char* base = (char*)d_ws;
  US*    KT_hi  = (US*)(base);                  // [0,32)   -> later RTf_hi
  US*    KT_lo  = (US*)(base + 32 * MiB);       // [32,64)  -> later RTf_lo
  US*    RTf_hi = KT_hi;
  US*    RTf_lo = KT_lo;
  float* zx     = (float*)(base + 64 * MiB);    // [64,128) -> later WSTf
  US*    WSTf_hi = (US*)(base + 64 * MiB);
  US*    WSTf_lo = (US*)(base + 96 * MiB);
  char*  C = base + 128 * MiB;
  US* comp_hi = (US*)(C);
  US* comp_lo = (US*)(C + 8 * MiB);
  US* flat_hi = (US*)(C + 16 * MiB);
  US* flat_lo = (US*)(C + 24 * MiB);
  US* xs_hi   = (US*)(C + 32 * MiB);
  US* xs_lo   = (US*)(C + 40 * MiB);
  char* Mz = base + 176 * MiB;
  float* mproj = (float*)(Mz);
  float* cbuf  = (float*)(Mz + 64 * 1024);
  US* hh[2]; US* hl[2];
  hh[0] = (US*)(Mz + 384 * 1024);
  hl[0] = (US*)(Mz + 512 * 1024);
  hh[1] = (US*)(Mz + 640 * 1024);
  hl[1] = (US*)(Mz + 768 * 1024);

  // ---- prep ----
  split_kernel<<<4096, 256, 0, stream>>>(inputs, flat_hi, flat_lo, 1048576);
  split_kernel<<<4096, 256, 0, stream>>>(comp,   comp_hi, comp_lo, 1048576);
  mproj_kernel<<<2048, 256, 0, stream>>>(mean, comp, mproj);
  build_kt<<<4096, 256, 0, stream>>>(Kmat, KT_hi, KT_lo);
  zero_kernel<<<256, 256, 0, stream>>>(cbuf, hh[0], hl[0]);

  // xs = (flat - mean) @ comp^T   (2048 x 2048)
  gemm128<2, 0><<<512, 256, 0, stream>>>(flat_hi, flat_lo, comp_hi, comp_lo,
                                         mproj, xs_hi, xs_lo, 16, 2048);
  // zx = xs @ K  (2048 x 8192, gate-interleaved cols)
  gemm128<4, 1><<<1024, 256, 0, stream>>>(xs_hi, xs_lo, KT_hi, KT_lo,
                                          nullptr, (US*)zx, nullptr, 16, 8192);
  // RTf (fragment-linear R^T) over the now-dead KT region
  build_wfrag<false><<<4096, 256, 0, stream>>>(Rmat, nullptr, RTf_hi, RTf_lo);

  // ---- 64 encoder steps: z = zx[s] + h @ R^T ----
  for (int s = 0; s < 64; ++s) {
    int par = s & 1;
    lstm_step<<<512, 512, 0, stream>>>(hh[par], hl[par], RTf_hi, RTf_lo,
                                       zx + (size_t)s * 32 * 8192,
                                       bias, cbuf, hh[1 - par], hl[1 - par],
                                       out, -1);
  }
  // WSTf = (K + R)^T fragment-linear, over the now-dead zx region
  build_wfrag<true><<<4096, 256, 0, stream>>>(Kmat, Rmat, WSTf_hi, WSTf_lo);
  // ---- 24 decoder steps: z = h @ (K+R)^T ----
  for (int s = 64; s < 88; ++s) {
    int par = s & 1;
    lstm_step<<<512, 512, 0, stream>>>(hh[par], hl[par], WSTf_hi, WSTf_lo,
                                       nullptr,
                                       bias, cbuf, hh[1 - par], hl[1 - par],
                                       out, s - 64);
  }
}